// Round 1
// baseline (1395.973 us; speedup 1.0000x reference)
//
#include <hip/hip_runtime.h>
#include <math.h>

#define N 1024
#define LOGN 10
#define BATCH 16
#define CH 3
#define BC 48
#define ROWS (BC * N)        // 49152
#define OUTHW 224
#define ROWF 2048            // floats per row slot in workspace (complex row = 2048 floats)
#define KSCALE (1024.0f / 224.0f)   // antialias kernel scale (inv_scale)
#define SCALE  (224.0f / 1024.0f)

__device__ __forceinline__ float2 cmul(float2 a, float2 b) {
  return make_float2(a.x * b.x - a.y * b.y, a.x * b.y + a.y * b.x);
}

__device__ __forceinline__ void make_twiddles(float2* tw, int t) {
  for (int i = t; i < N / 2; i += 256) {
    float ang = -6.28318530717958647692f * ((float)i / (float)N);
    float s, c;
    sincosf(ang, &s, &c);
    tw[i] = make_float2(c, s);
  }
}

// In-LDS 1024-pt radix-2 DIT FFT; input must be stored bit-reversed. 256 threads.
__device__ void fft1024(float2* data, const float2* tw, int t) {
  for (int s = 1; s <= LOGN; ++s) {
    __syncthreads();
    const int half = 1 << (s - 1);
    const int shift = LOGN - s;
#pragma unroll
    for (int k = 0; k < 2; ++k) {
      int bidx = t + k * 256;              // 0..511
      int pos = bidx & (half - 1);
      int grp = bidx >> (s - 1);
      int i1 = (grp << s) + pos;
      int i2 = i1 + half;
      float2 w = tw[pos << shift];
      float2 u = data[i1];
      float2 v = cmul(data[i2], w);
      data[i1] = make_float2(u.x + v.x, u.y + v.y);
      data[i2] = make_float2(u.x - v.x, u.y - v.y);
    }
  }
  __syncthreads();
}

// Pass 1: row FFT with (-1)^(h+w) modulation (=> output is fftshifted in both dims).
__global__ __launch_bounds__(256) void k_rowfft(const float* __restrict__ in,
                                                float2* __restrict__ A) {
  __shared__ float2 data[N];
  __shared__ float2 tw[N / 2];
  const int r = blockIdx.x;          // 0..ROWS-1 : (bc*1024 + h)
  const int t = threadIdx.x;
  const int h = r & (N - 1);
  make_twiddles(tw, t);
  const float* row = in + (size_t)r * N;
  for (int i = t; i < N; i += 256) {
    float v = row[i];
    if ((h + i) & 1) v = -v;
    int p = __brev((unsigned)i) >> (32 - LOGN);
    data[p] = make_float2(v, 0.0f);
  }
  fft1024(data, tw, t);
  float2* dst = A + (size_t)r * N;
  for (int i = t; i < N; i += 256) dst[i] = data[i];
}

// Pass 2: in-place transpose of each 1024x1024 complex matrix via tile pairs.
__global__ __launch_bounds__(256) void k_transpose(float2* __restrict__ A) {
  const int p0 = blockIdx.x % 528;
  const int bc = blockIdx.x / 528;
  int ti = 0, rem = p0;
  while (rem >= 32 - ti) { rem -= 32 - ti; ti++; }
  const int tj = ti + rem;
  __shared__ float2 Ta[32][33];
  __shared__ float2 Tb[32][33];
  float2* M = A + (size_t)bc * N * N;
  const int t = threadIdx.x;
  for (int e = t; e < 1024; e += 256) {
    int rr = e >> 5, cc = e & 31;
    Ta[rr][cc] = M[(size_t)(ti * 32 + rr) * N + tj * 32 + cc];
    Tb[rr][cc] = M[(size_t)(tj * 32 + rr) * N + ti * 32 + cc];
  }
  __syncthreads();
  for (int e = t; e < 1024; e += 256) {
    int rr = e >> 5, cc = e & 31;
    M[(size_t)(ti * 32 + rr) * N + tj * 32 + cc] = Tb[cc][rr];
    M[(size_t)(tj * 32 + rr) * N + ti * 32 + cc] = Ta[cc][rr];
  }
}

__global__ void k_init_minmax(int* __restrict__ mnmx) {
  int t = threadIdx.x;
  if (t < BATCH) mnmx[t] = 0x7F800000;          // +inf (min slots)
  else if (t < 2 * BATCH) mnmx[t] = 0;          // 0 (max slots; spec >= 0)
}

// Pass 3: column FFT (rows of transposed A) + log1p(|.|) + min/max atomics.
// Writes packed fp32 spec into first half of the row's own slot.
__global__ __launch_bounds__(256) void k_colfft(float* __restrict__ WS,
                                                int* __restrict__ mnmx) {
  __shared__ float2 data[N];
  __shared__ float2 tw[N / 2];
  __shared__ float rmin[256];
  __shared__ float rmax[256];
  const int r = blockIdx.x;          // bc*1024 + sx
  const int t = threadIdx.x;
  const int bc = r >> LOGN;
  const int b = bc / CH;
  make_twiddles(tw, t);
  const float2* src = (const float2*)(WS + (size_t)r * ROWF);
  for (int i = t; i < N; i += 256) {
    int p = __brev((unsigned)i) >> (32 - LOGN);
    data[p] = src[i];
  }
  fft1024(data, tw, t);
  float lmin = 3.4e38f, lmax = 0.0f;
  float* dst = WS + (size_t)r * ROWF;
  for (int i = t; i < N; i += 256) {
    float2 v = data[i];
    float sp = log1pf(sqrtf(v.x * v.x + v.y * v.y));
    dst[i] = sp;
    lmin = fminf(lmin, sp);
    lmax = fmaxf(lmax, sp);
  }
  rmin[t] = lmin; rmax[t] = lmax;
  __syncthreads();
  for (int off = 128; off > 0; off >>= 1) {
    if (t < off) {
      rmin[t] = fminf(rmin[t], rmin[t + off]);
      rmax[t] = fmaxf(rmax[t], rmax[t + off]);
    }
    __syncthreads();
  }
  if (t == 0) {
    atomicMin(&mnmx[b], __float_as_int(rmin[0]));
    atomicMax(&mnmx[BATCH + b], __float_as_int(rmax[0]));
  }
}

// Antialiased triangle-kernel weights (jax.image.resize bilinear, antialias=True).
__device__ __forceinline__ float resize224(const float* __restrict__ buf, int o) {
  float x = ((float)o + 0.5f) * KSCALE - 0.5f;
  int jlo = (int)ceilf(x - KSCALE);
  int jhi = (int)floorf(x + KSCALE);
  jlo = jlo < 0 ? 0 : jlo;
  jhi = jhi > N - 1 ? N - 1 : jhi;
  float ssum = 0.0f, acc = 0.0f;
  for (int j = jlo; j <= jhi; ++j) {
    float w = 1.0f - fabsf((float)j - x) * SCALE;
    w = fmaxf(w, 0.0f);
    ssum += w;
    acc += w * buf[j];
  }
  return acc / ssum;
}

// Pass 4: contract sy (contiguous dim). T1[sx][oh] stored in spare half of row slot.
__global__ __launch_bounds__(256) void k_resize1(float* __restrict__ WS) {
  __shared__ float rowbuf[N];
  const int r = blockIdx.x;          // bc*1024 + sx
  const int t = threadIdx.x;
  const float* src = WS + (size_t)r * ROWF;
  for (int i = t; i < N; i += 256) rowbuf[i] = src[i];
  __syncthreads();
  if (t < OUTHW) {
    WS[(size_t)r * ROWF + N + t] = resize224(rowbuf, t);
  }
}

// Pass 5: contract sx (strided dim) + per-sample normalization + final write.
__global__ __launch_bounds__(256) void k_resize2(const float* __restrict__ WS,
                                                 const int* __restrict__ mnmx,
                                                 float* __restrict__ out) {
  __shared__ float colbuf[N];
  const int oh = blockIdx.x % OUTHW;
  const int bc = blockIdx.x / OUTHW;
  const int b = bc / CH;
  const int t = threadIdx.x;
  const float* base = WS + (size_t)bc * N * ROWF + N + oh;
  for (int i = t; i < N; i += 256) colbuf[i] = base[(size_t)i * ROWF];
  __syncthreads();
  const float mn = __int_as_float(mnmx[b]);
  const float mx = __int_as_float(mnmx[BATCH + b]);
  const float inv = 1.0f / (mx - mn + 1e-8f);
  if (t < OUTHW) {
    float v = resize224(colbuf, t);
    out[((size_t)bc * OUTHW + oh) * OUTHW + t] = (v - mn) * inv;
  }
}

extern "C" void kernel_launch(void* const* d_in, const int* in_sizes, int n_in,
                              void* d_out, int out_size, void* d_ws, size_t ws_size,
                              hipStream_t stream) {
  const float* in = (const float*)d_in[0];
  float* out = (float*)d_out;
  float2* A = (float2*)d_ws;
  float* WS = (float*)d_ws;
  int* mnmx = (int*)((char*)d_ws + (size_t)BC * N * N * sizeof(float2));

  k_rowfft<<<ROWS, 256, 0, stream>>>(in, A);
  k_transpose<<<BC * 528, 256, 0, stream>>>(A);
  k_init_minmax<<<1, 64, 0, stream>>>(mnmx);
  k_colfft<<<ROWS, 256, 0, stream>>>(WS, mnmx);
  k_resize1<<<ROWS, 256, 0, stream>>>(WS);
  k_resize2<<<BC * OUTHW, 256, 0, stream>>>(WS, mnmx, out);
}

// Round 2
// 922.057 us; speedup vs baseline: 1.5140x; 1.5140x over previous
//
#include <hip/hip_runtime.h>
#include <math.h>

#define N 1024
#define BATCH 16
#define CH 3
#define BC 48
#define OUTHW 224
#define ROWF 2048
#define KSCALE (1024.0f / 224.0f)
#define SCALE  (224.0f / 1024.0f)
#define ABYTES ((size_t)BC * N * N * 8)   // 384 MiB complex workspace

// ---------- radix-4 Stockham FFT: 1024 pts, 256 threads, SoA double-buffer ----------
// Input natural order in re0/im0; output natural order in re1/im1 (5 stages, odd swaps).
// Reads are stride-256 (conflict-free); stage-0 writes are contiguous float4.
__device__ __forceinline__ void fft1024_r4(float* __restrict__ re0, float* __restrict__ im0,
                                           float* __restrict__ re1, float* __restrict__ im1,
                                           const float2* __restrict__ twg, int t) {
  float* rs = re0; float* is_ = im0; float* rd = re1; float* id_ = im1;
#pragma unroll
  for (int stage = 0; stage < 5; ++stage) {
    const int Ns = 1 << (2 * stage);
    __syncthreads();
    const int j = t;
    const int jm = j & (Ns - 1);
    float ar = rs[j],       ai = is_[j];
    float br = rs[j + 256], bi = is_[j + 256];
    float cr = rs[j + 512], ci = is_[j + 512];
    float dr = rs[j + 768], di = is_[j + 768];
    float t1r, t1i, t2r, t2i, t3r, t3i;
    if (stage == 0) {          // all twiddles are 1
      t1r = br; t1i = bi; t2r = cr; t2i = ci; t3r = dr; t3i = di;
    } else {
      const int m1 = jm * (256 >> (2 * stage));      // angle = -2*pi*m1/1024
      float2 w1 = twg[m1];
      float2 w2 = twg[2 * m1];
      float2 w3 = twg[3 * m1];                       // 3*m1 <= 765 < 1024
      t1r = br * w1.x - bi * w1.y; t1i = br * w1.y + bi * w1.x;
      t2r = cr * w2.x - ci * w2.y; t2i = cr * w2.y + ci * w2.x;
      t3r = dr * w3.x - di * w3.y; t3i = dr * w3.y + di * w3.x;
    }
    // radix-4 butterfly (forward): u3 = -i*(t1 - t3)
    float u0r = ar + t2r,  u0i = ai + t2i;
    float u1r = ar - t2r,  u1i = ai - t2i;
    float u2r = t1r + t3r, u2i = t1i + t3i;
    float u3r = t1i - t3i, u3i = t3r - t1r;
    float y0r = u0r + u2r, y0i = u0i + u2i;
    float y1r = u1r + u3r, y1i = u1i + u3i;
    float y2r = u0r - u2r, y2i = u0i - u2i;
    float y3r = u1r - u3r, y3i = u1i - u3i;
    if (stage == 0) {
      ((float4*)rd)[j]  = make_float4(y0r, y1r, y2r, y3r);
      ((float4*)id_)[j] = make_float4(y0i, y1i, y2i, y3i);
    } else {
      const int idx = ((j - jm) << 2) + jm;          // (j/Ns)*4Ns + jm
      rd[idx] = y0r; rd[idx + Ns] = y1r; rd[idx + 2 * Ns] = y2r; rd[idx + 3 * Ns] = y3r;
      id_[idx] = y0i; id_[idx + Ns] = y1i; id_[idx + 2 * Ns] = y2i; id_[idx + 3 * Ns] = y3i;
    }
    float* tmp;
    tmp = rs;  rs  = rd;  rd  = tmp;
    tmp = is_; is_ = id_; id_ = tmp;
  }
  __syncthreads();
}

__global__ void k_init(float2* __restrict__ tw, int* __restrict__ mnmx) {
  int g = blockIdx.x * 256 + threadIdx.x;
  if (g < 1024) {
    float ang = -6.283185307179586f * ((float)g / 1024.0f);
    float s, c;
    sincosf(ang, &s, &c);
    tw[g] = make_float2(c, s);
  }
  if (g < BATCH) mnmx[g] = 0x7F800000;       // +inf (min slots)
  else if (g < 2 * BATCH) mnmx[g] = 0;       // 0 (max slots; spec >= 0)
}

// Pass 1: real row-pair packing z = row(2q) + i*row(2q+1), both modulated by (-1)^(h+w)
// (modulation keeps rows real => Hermitian unpack valid; output is pre-fftshifted).
__global__ __launch_bounds__(256) void k_rowfft(const float* __restrict__ in,
                                                float2* __restrict__ A,
                                                const float2* __restrict__ twg) {
  __shared__ __align__(16) float re0[N], im0[N], re1[N], im1[N];
  const int q  = blockIdx.x;           // 0..BC*512-1
  const int bc = q >> 9;
  const int h0 = (q & 511) << 1;       // even row; h1 = h0+1
  const int t  = threadIdx.x;
  const float4* r04 = (const float4*)(in + ((size_t)bc << 20) + ((size_t)h0 << 10));
  const float4* r14 = r04 + 256;
  float4 va = r04[t];
  float4 vb = r14[t];
  // (-1)^(h0+w) with h0 even: +,-,+,-   ;  (-1)^(h1+w): -,+,-,+
  ((float4*)re0)[t] = make_float4(va.x, -va.y, va.z, -va.w);
  ((float4*)im0)[t] = make_float4(-vb.x, vb.y, -vb.z, vb.w);
  fft1024_r4(re0, im0, re1, im1, twg, t);
  // Hermitian unpack: P=Z[k], Q=conj(Z[(N-k)%N]); A=(P+Q)/2, B=-i(P-Q)/2
  float2* outA = A + ((size_t)bc << 20) + ((size_t)h0 << 10);
  float2* outB = outA + N;
  for (int i = t; i < N; i += 256) {
    int nk = (N - i) & (N - 1);
    float pr = re1[i], pi = im1[i];
    float mr = re1[nk], mi = im1[nk];
    outA[i] = make_float2(0.5f * (pr + mr), 0.5f * (pi - mi));
    outB[i] = make_float2(0.5f * (pi + mi), 0.5f * (mr - pr));
  }
}

// Pass 2: in-place tile-pair transpose; only tiles feeding output rows 0..512 needed.
__global__ __launch_bounds__(256) void k_transpose(float2* __restrict__ A) {
  const int p0 = blockIdx.x % 528;
  const int bc = blockIdx.x / 528;
  int ti = 0, rem = p0;
  while (rem >= 32 - ti) { rem -= 32 - ti; ti++; }
  const int tj = ti + rem;            // ti <= tj
  if (ti > 16) return;                // colfft only reads rows 0..512 (tile rows 0..16)
  __shared__ float2 Ta[32][33];
  __shared__ float2 Tb[32][33];
  float2* M = A + (size_t)bc * N * N;
  const int t = threadIdx.x;
  for (int e = t; e < 1024; e += 256) {
    int rr = e >> 5, cc = e & 31;
    Ta[rr][cc] = M[(size_t)(ti * 32 + rr) * N + tj * 32 + cc];
    Tb[rr][cc] = M[(size_t)(tj * 32 + rr) * N + ti * 32 + cc];
  }
  __syncthreads();
  for (int e = t; e < 1024; e += 256) {
    int rr = e >> 5, cc = e & 31;
    M[(size_t)(ti * 32 + rr) * N + tj * 32 + cc] = Tb[cc][rr];
    M[(size_t)(tj * 32 + rr) * N + ti * 32 + cc] = Ta[cc][rr];
  }
}

// Pass 3: column FFT for sx=0..512 only; 2D-Hermitian mirror fills sx=513..1023.
// Spec[si][sj] = Spec[(N-si)%N][(N-sj)%N] for real (modulated) input.
__global__ __launch_bounds__(256) void k_colfft(float* __restrict__ WS,
                                                int* __restrict__ mnmx,
                                                const float2* __restrict__ twg) {
  __shared__ __align__(16) float re0[N], im0[N], re1[N], im1[N];
  __shared__ float rmin[256], rmax[256];
  const int bc = blockIdx.x / 513;
  const int sx = blockIdx.x % 513;
  const int b  = bc / CH;
  const int t  = threadIdx.x;
  const int r  = (bc << 10) + sx;
  const float4* src4 = (const float4*)(WS + (size_t)r * ROWF);
  for (int i = t; i < 512; i += 256) {
    float4 v = src4[i];
    re0[2 * i] = v.x; im0[2 * i] = v.y;
    re0[2 * i + 1] = v.z; im0[2 * i + 1] = v.w;
  }
  fft1024_r4(re0, im0, re1, im1, twg, t);
  float lmin = 3.4e38f, lmax = 0.0f;
  for (int i = t; i < N; i += 256) {
    float xr = re1[i], xi = im1[i];
    float sp = log1pf(sqrtf(xr * xr + xi * xi));
    re0[i] = sp;                                   // spec row staged for mirrored write
    lmin = fminf(lmin, sp); lmax = fmaxf(lmax, sp);
  }
  rmin[t] = lmin; rmax[t] = lmax;
  __syncthreads();
  for (int off = 128; off > 0; off >>= 1) {
    if (t < off) { rmin[t] = fminf(rmin[t], rmin[t + off]); rmax[t] = fmaxf(rmax[t], rmax[t + off]); }
    __syncthreads();
  }
  float* dst = WS + (size_t)r * ROWF;
  for (int i = t; i < N; i += 256) dst[i] = re0[i];
  if (sx != 0 && sx != 512) {
    float* dst2 = WS + (size_t)((bc << 10) + (N - sx)) * ROWF;
    for (int i = t; i < N; i += 256) dst2[i] = re0[(N - i) & (N - 1)];
  }
  if (t == 0) {
    atomicMin(&mnmx[b], __float_as_int(rmin[0]));
    atomicMax(&mnmx[BATCH + b], __float_as_int(rmax[0]));
  }
}

// Antialiased triangle weights (jax.image.resize bilinear, antialias=True).
__device__ __forceinline__ float resize224(const float* __restrict__ buf, int o) {
  float x = ((float)o + 0.5f) * KSCALE - 0.5f;
  int jlo = (int)ceilf(x - KSCALE);
  int jhi = (int)floorf(x + KSCALE);
  jlo = jlo < 0 ? 0 : jlo;
  jhi = jhi > N - 1 ? N - 1 : jhi;
  float ssum = 0.0f, acc = 0.0f;
  for (int j = jlo; j <= jhi; ++j) {
    float w = 1.0f - fabsf((float)j - x) * SCALE;
    w = fmaxf(w, 0.0f);
    ssum += w;
    acc += w * buf[j];
  }
  return acc / ssum;
}

// Pass 4: contract sy (contiguous). Store T1 transposed: T1[bc][oh][sx] in the spare
// half of row slots (row (bc,oh), offset 1024+sx) so pass 5 reads are unit-stride.
__global__ __launch_bounds__(256) void k_resize1(float* __restrict__ WS) {
  __shared__ float rowbuf[N];
  const int r  = blockIdx.x;          // bc*1024 + sx
  const int bc = r >> 10;
  const int sx = r & 1023;
  const int t  = threadIdx.x;
  const float* src = WS + (size_t)r * ROWF;
  for (int i = t; i < N; i += 256) rowbuf[i] = src[i];
  __syncthreads();
  if (t < OUTHW) {
    WS[((size_t)((bc << 10) + t) * ROWF) + N + sx] = resize224(rowbuf, t);
  }
}

// Pass 5: contract sx (now contiguous) + per-sample normalization.
__global__ __launch_bounds__(256) void k_resize2(const float* __restrict__ WS,
                                                 const int* __restrict__ mnmx,
                                                 float* __restrict__ out) {
  __shared__ float colbuf[N];
  const int oh = blockIdx.x % OUTHW;
  const int bc = blockIdx.x / OUTHW;
  const int b  = bc / CH;
  const int t  = threadIdx.x;
  const float* base = WS + ((size_t)((bc << 10) + oh) * ROWF) + N;
  for (int i = t; i < N; i += 256) colbuf[i] = base[i];
  __syncthreads();
  const float mn = __int_as_float(mnmx[b]);
  const float mx = __int_as_float(mnmx[BATCH + b]);
  const float inv = 1.0f / (mx - mn + 1e-8f);
  if (t < OUTHW) {
    float v = resize224(colbuf, t);
    out[((size_t)bc * OUTHW + oh) * OUTHW + t] = (v - mn) * inv;
  }
}

extern "C" void kernel_launch(void* const* d_in, const int* in_sizes, int n_in,
                              void* d_out, int out_size, void* d_ws, size_t ws_size,
                              hipStream_t stream) {
  const float* in = (const float*)d_in[0];
  float* out = (float*)d_out;
  float* WS = (float*)d_ws;
  float2* A = (float2*)d_ws;
  int* mnmx = (int*)((char*)d_ws + ABYTES);
  float2* twg = (float2*)((char*)d_ws + ABYTES + 128);

  k_init<<<4, 256, 0, stream>>>(twg, mnmx);
  k_rowfft<<<BC * 512, 256, 0, stream>>>(in, A, twg);
  k_transpose<<<BC * 528, 256, 0, stream>>>(A);
  k_colfft<<<BC * 513, 256, 0, stream>>>(WS, mnmx, twg);
  k_resize1<<<BC * N, 256, 0, stream>>>(WS);
  k_resize2<<<BC * OUTHW, 256, 0, stream>>>(WS, mnmx, out);
}

// Round 3
// 733.338 us; speedup vs baseline: 1.9036x; 1.2573x over previous
//
#include <hip/hip_runtime.h>
#include <math.h>

#define N 1024
#define BATCH 16
#define CH 3
#define BC 48
#define OUTHW 224
#define KSCALE (1024.0f / 224.0f)
#define SCALE  (224.0f / 1024.0f)
#define ABYTES ((size_t)BC * N * N * 8)      // 384 MiB complex workspace
#define T1OFF  (768 * 2048)                  // float offset of T1 inside each image's A slab
#define LP(i)  ((i) + ((i) >> 5))            // LDS bank-conflict pad (<=2-way everywhere, 4-way @s2)

// ---------- radix-4 Stockham FFT: 1024 pts, 256 threads, padded SoA double-buffer ----------
// Input natural order in re0/im0 (LP-indexed); output natural order in re1/im1 (LP-indexed).
__device__ __forceinline__ void fft1024_r4(float* __restrict__ re0, float* __restrict__ im0,
                                           float* __restrict__ re1, float* __restrict__ im1,
                                           const float2* __restrict__ twg, int t) {
  float* rs = re0; float* is_ = im0; float* rd = re1; float* id_ = im1;
#pragma unroll
  for (int stage = 0; stage < 5; ++stage) {
    const int Ns = 1 << (2 * stage);
    __syncthreads();
    const int j = t;
    const int jm = j & (Ns - 1);
    float ar = rs[LP(j)],       ai = is_[LP(j)];
    float br = rs[LP(j + 256)], bi = is_[LP(j + 256)];
    float cr = rs[LP(j + 512)], ci = is_[LP(j + 512)];
    float dr = rs[LP(j + 768)], di = is_[LP(j + 768)];
    float t1r, t1i, t2r, t2i, t3r, t3i;
    if (stage == 0) {
      t1r = br; t1i = bi; t2r = cr; t2i = ci; t3r = dr; t3i = di;
    } else {
      const int m1 = jm * (256 >> (2 * stage));
      float2 w1 = twg[m1];
      float2 w2 = twg[2 * m1];
      float2 w3 = twg[3 * m1];
      t1r = br * w1.x - bi * w1.y; t1i = br * w1.y + bi * w1.x;
      t2r = cr * w2.x - ci * w2.y; t2i = cr * w2.y + ci * w2.x;
      t3r = dr * w3.x - di * w3.y; t3i = dr * w3.y + di * w3.x;
    }
    float u0r = ar + t2r,  u0i = ai + t2i;
    float u1r = ar - t2r,  u1i = ai - t2i;
    float u2r = t1r + t3r, u2i = t1i + t3i;
    float u3r = t1i - t3i, u3i = t3r - t1r;
    const int idx = ((j - jm) << 2) + jm;
    rd[LP(idx)]          = u0r + u2r;  id_[LP(idx)]          = u0i + u2i;
    rd[LP(idx + Ns)]     = u1r + u3r;  id_[LP(idx + Ns)]     = u1i + u3i;
    rd[LP(idx + 2 * Ns)] = u0r - u2r;  id_[LP(idx + 2 * Ns)] = u0i - u2i;
    rd[LP(idx + 3 * Ns)] = u1r - u3r;  id_[LP(idx + 3 * Ns)] = u1i - u3i;
    float* tmp;
    tmp = rs;  rs  = rd;  rd  = tmp;
    tmp = is_; is_ = id_; id_ = tmp;
  }
  __syncthreads();
}

__global__ void k_init(float2* __restrict__ tw, int* __restrict__ mnmx) {
  int g = blockIdx.x * 256 + threadIdx.x;
  if (g < 1024) {
    float ang = -6.283185307179586f * ((float)g / 1024.0f);
    float s, c;
    sincosf(ang, &s, &c);
    tw[g] = make_float2(c, s);
  }
  if (g < BATCH) mnmx[g] = 0x7F800000;       // +inf (min slots)
  else if (g < 2 * BATCH) mnmx[g] = 0;       // 0 (max slots; spec >= 0)
}

// Pass 1: real row-pair packing z = row(2q) + i*row(2q+1), (-1)^(h+w) modulated
// (pre-fftshift). Hermitian unpack; store only bins v=0..512 (row spectra of real
// input are Hermitian in v; the rest is reconstructed via 2D symmetry in colfft).
__global__ __launch_bounds__(256) void k_rowfft(const float* __restrict__ in,
                                                float2* __restrict__ A,
                                                const float2* __restrict__ twg) {
  __shared__ float re0[1056], im0[1056], re1[1056], im1[1056];
  const int q  = blockIdx.x;           // 0..BC*512-1
  const int bc = q >> 9;
  const int h0 = (q & 511) << 1;
  const int t  = threadIdx.x;
  const float4* r04 = (const float4*)(in + ((size_t)bc << 20) + ((size_t)h0 << 10));
  const float4* r14 = r04 + 256;
  float4 va = r04[t];
  float4 vb = r14[t];
  const int p4 = 4 * t;
  // h0 even: signs +,-,+,- ; h1 odd: -,+,-,+
  re0[LP(p4)]     =  va.x; re0[LP(p4 + 1)] = -va.y;
  re0[LP(p4 + 2)] =  va.z; re0[LP(p4 + 3)] = -va.w;
  im0[LP(p4)]     = -vb.x; im0[LP(p4 + 1)] =  vb.y;
  im0[LP(p4 + 2)] = -vb.z; im0[LP(p4 + 3)] =  vb.w;
  fft1024_r4(re0, im0, re1, im1, twg, t);
  float2* outA = A + ((size_t)bc << 20) + ((size_t)h0 << 10);
  float2* outB = outA + N;
  for (int i = t; i < 513; i += 256) {
    int nk = (N - i) & (N - 1);
    float pr = re1[LP(i)],  pi = im1[LP(i)];
    float mr = re1[LP(nk)], mi = im1[LP(nk)];
    outA[i] = make_float2(0.5f * (pr + mr), 0.5f * (pi - mi));
    outB[i] = make_float2(0.5f * (pi + mi), 0.5f * (mr - pr));
  }
}

// Pass 2: in-place transpose restricted to what colfft reads (rows 0..512 of A^T).
// Corner (17x17 tile block) via pair swaps; columns 17..31 via one-way copies
// (their sources/dests are disjoint from all other reads -> no ordering hazard).
__global__ __launch_bounds__(256) void k_transpose(float2* __restrict__ A) {
  const int p  = blockIdx.x % 408;
  const int bc = blockIdx.x / 408;
  float2* M = A + ((size_t)bc << 20);
  const int t = threadIdx.x;
  __shared__ float2 Ta[32][33];
  __shared__ float2 Tb[32][33];
  if (p < 153) {
    int ti = 0, rem = p;
    while (rem >= 17 - ti) { rem -= 17 - ti; ti++; }
    const int tj = ti + rem;
    for (int e = t; e < 1024; e += 256) {
      int rr = e >> 5, cc = e & 31;
      Ta[rr][cc] = M[(size_t)(ti * 32 + rr) * N + tj * 32 + cc];
      Tb[rr][cc] = M[(size_t)(tj * 32 + rr) * N + ti * 32 + cc];
    }
    __syncthreads();
    for (int e = t; e < 1024; e += 256) {
      int rr = e >> 5, cc = e & 31;
      M[(size_t)(ti * 32 + rr) * N + tj * 32 + cc] = Tb[cc][rr];
      M[(size_t)(tj * 32 + rr) * N + ti * 32 + cc] = Ta[cc][rr];
    }
  } else {
    const int qq = p - 153;
    const int r = qq % 17;          // dest tile row 0..16
    const int c = 17 + qq / 17;     // dest tile col 17..31
    for (int e = t; e < 1024; e += 256) {
      int rr = e >> 5, cc = e & 31;
      Ta[rr][cc] = M[(size_t)(c * 32 + rr) * N + r * 32 + cc];
    }
    __syncthreads();
    for (int e = t; e < 1024; e += 256) {
      int rr = e >> 5, cc = e & 31;
      M[(size_t)(r * 32 + rr) * N + c * 32 + cc] = Ta[cc][rr];
    }
  }
}

// Pass 3: column FFT for v=0..512 + log1p|.| + min/max + FUSED u-contraction
// (resize over the height dim) for both v=sx and the 2D-Hermitian mirror v=N-sx
// (mirror column = reversed read of the same LDS buffer). Writes T1[v][oh].
__global__ __launch_bounds__(256) void k_colfft(float2* __restrict__ A,
                                                int* __restrict__ mnmx,
                                                const float2* __restrict__ twg) {
  __shared__ float re0[1056], im0[1056], re1[1056], im1[1056];
  __shared__ float rmin[256], rmax[256];
  const int bc = blockIdx.x / 513;
  const int sx = blockIdx.x % 513;
  const int b  = bc / CH;
  const int t  = threadIdx.x;
  float2* Abc = A + ((size_t)bc << 20);
  const float4* src4 = (const float4*)(Abc + ((size_t)sx << 10));
  for (int i = t; i < 512; i += 256) {
    float4 v = src4[i];
    re0[LP(2 * i)]     = v.x; im0[LP(2 * i)]     = v.y;
    re0[LP(2 * i + 1)] = v.z; im0[LP(2 * i + 1)] = v.w;
  }
  fft1024_r4(re0, im0, re1, im1, twg, t);
  float* spec = re0;                       // plain-indexed reuse (re0 dead post-FFT)
  float lmin = 3.4e38f, lmax = 0.0f;
  for (int i = t; i < N; i += 256) {
    float xr = re1[LP(i)], xi = im1[LP(i)];
    float sp = log1pf(sqrtf(xr * xr + xi * xi));
    spec[i] = sp;
    lmin = fminf(lmin, sp); lmax = fmaxf(lmax, sp);
  }
  rmin[t] = lmin; rmax[t] = lmax;
  __syncthreads();
  for (int off = 128; off > 0; off >>= 1) {
    if (t < off) { rmin[t] = fminf(rmin[t], rmin[t + off]); rmax[t] = fmaxf(rmax[t], rmax[t + off]); }
    __syncthreads();
  }
  if (t == 0) {
    atomicMin(&mnmx[b], __float_as_int(rmin[0]));
    atomicMax(&mnmx[BATCH + b], __float_as_int(rmax[0]));
  }
  float* T1 = (float*)Abc + T1OFF;
  if (t < OUTHW) {
    float x = ((float)t + 0.5f) * KSCALE - 0.5f;
    int jlo = (int)ceilf(x - KSCALE); if (jlo < 0) jlo = 0;
    int jhi = (int)floorf(x + KSCALE); if (jhi > N - 1) jhi = N - 1;
    float ssum = 0.0f, acc = 0.0f, accm = 0.0f;
    for (int j = jlo; j <= jhi; ++j) {
      float w = 1.0f - fabsf((float)j - x) * SCALE;
      w = fmaxf(w, 0.0f);
      ssum += w;
      acc  += w * spec[j];
      accm += w * spec[(N - j) & (N - 1)];
    }
    float inv = 1.0f / ssum;
    T1[(size_t)sx * OUTHW + t] = acc * inv;
    if (sx != 0 && sx != 512) T1[(size_t)(N - sx) * OUTHW + t] = accm * inv;
  }
}

// Pass 4: contract v (T1 rows are contiguous per oh-window) + normalization.
__global__ __launch_bounds__(256) void k_resize2(const float2* __restrict__ A,
                                                 const int* __restrict__ mnmx,
                                                 float* __restrict__ out) {
  __shared__ float win[11 * OUTHW];
  const int ow = blockIdx.x % OUTHW;
  const int bc = blockIdx.x / OUTHW;
  const int b  = bc / CH;
  const int t  = threadIdx.x;
  const float* T1 = (const float*)(A + ((size_t)bc << 20)) + T1OFF;
  float x = ((float)ow + 0.5f) * KSCALE - 0.5f;
  int jlo = (int)ceilf(x - KSCALE); if (jlo < 0) jlo = 0;
  int jhi = (int)floorf(x + KSCALE); if (jhi > N - 1) jhi = N - 1;
  const int nel = (jhi - jlo + 1) * OUTHW;
  const float* src = T1 + (size_t)jlo * OUTHW;
  for (int e = t; e < nel; e += 256) win[e] = src[e];
  __syncthreads();
  const float mn = __int_as_float(mnmx[b]);
  const float mx = __int_as_float(mnmx[BATCH + b]);
  const float inv = 1.0f / (mx - mn + 1e-8f);
  if (t < OUTHW) {
    float ssum = 0.0f, acc = 0.0f;
    for (int j = jlo; j <= jhi; ++j) {
      float w = 1.0f - fabsf((float)j - x) * SCALE;
      w = fmaxf(w, 0.0f);
      ssum += w;
      acc += w * win[(j - jlo) * OUTHW + t];
    }
    float v = acc / ssum;
    out[((size_t)bc * OUTHW + t) * OUTHW + ow] = (v - mn) * inv;
  }
}

extern "C" void kernel_launch(void* const* d_in, const int* in_sizes, int n_in,
                              void* d_out, int out_size, void* d_ws, size_t ws_size,
                              hipStream_t stream) {
  const float* in = (const float*)d_in[0];
  float* out = (float*)d_out;
  float2* A = (float2*)d_ws;
  int* mnmx = (int*)((char*)d_ws + ABYTES);
  float2* twg = (float2*)((char*)d_ws + ABYTES + 128);

  k_init<<<4, 256, 0, stream>>>(twg, mnmx);
  k_rowfft<<<BC * 512, 256, 0, stream>>>(in, A, twg);
  k_transpose<<<BC * 408, 256, 0, stream>>>(A);
  k_colfft<<<BC * 513, 256, 0, stream>>>(A, mnmx, twg);
  k_resize2<<<BC * OUTHW, 256, 0, stream>>>(A, mnmx, out);
}

// Round 4
// 645.425 us; speedup vs baseline: 2.1629x; 1.1362x over previous
//
#include <hip/hip_runtime.h>
#include <math.h>

#define N 1024
#define BATCH 16
#define CH 3
#define BC 48
#define OUTHW 224
#define KSCALE (1024.0f / 224.0f)
#define SCALE  (224.0f / 1024.0f)
#define ABYTES ((size_t)BC * N * N * 8)      // 384 MiB complex workspace
#define T1OFF  (768 * 2048)                  // float offset of T1 inside each image's slab

// (ar,ai)*(br,bi) -> (dr,di); safe when d aliases a
#define CMUL(dr, di, ar, ai, br, bi) do {                         \
    float _r = (ar) * (br) - (ai) * (bi);                         \
    float _i = (ar) * (bi) + (ai) * (br);                         \
    (dr) = _r; (di) = _i; } while (0)

// forward DFT-4: X0=a+b+c+d, X1=a-ib-c+id(-i(b-d) form), X2=a-b+c-d, X3=a+ib-c-id
#define RADIX4(ar,ai,br,bi,cr,ci,dr,di, o0r,o0i,o1r,o1i,o2r,o2i,o3r,o3i) do { \
    float u0r=(ar)+(cr), u0i=(ai)+(ci);                           \
    float u1r=(ar)-(cr), u1i=(ai)-(ci);                           \
    float u2r=(br)+(dr), u2i=(bi)+(di);                           \
    float u3r=(bi)-(di), u3i=(dr)-(br);                           \
    (o0r)=u0r+u2r; (o0i)=u0i+u2i;                                 \
    (o1r)=u1r+u3r; (o1i)=u1i+u3i;                                 \
    (o2r)=u0r-u2r; (o2i)=u0i-u2i;                                 \
    (o3r)=u1r-u3r; (o3i)=u1i-u3i; } while (0)

// In-register natural-order 16-pt forward DFT (Stockham radix-4 x radix-4).
__device__ __forceinline__ void dft16(float* xr, float* xi) {
  // W16^{j*k} tables (row j, col k), W16 = e^{-2pi i/16}
  const float W16R[4][4] = {
    {1.f, 1.f, 1.f, 1.f},
    {1.f,  0.9238795325f,  0.7071067812f,  0.3826834324f},
    {1.f,  0.7071067812f,  0.0f,          -0.7071067812f},
    {1.f,  0.3826834324f, -0.7071067812f, -0.9238795325f}};
  const float W16I[4][4] = {
    {0.f, 0.f, 0.f, 0.f},
    {0.f, -0.3826834324f, -0.7071067812f, -0.9238795325f},
    {0.f, -0.7071067812f, -1.0f,          -0.7071067812f},
    {0.f, -0.9238795325f, -0.7071067812f,  0.3826834324f}};
  float tr[16], ti[16];
#pragma unroll
  for (int j = 0; j < 4; ++j) {
    RADIX4(xr[j],xi[j], xr[j+4],xi[j+4], xr[j+8],xi[j+8], xr[j+12],xi[j+12],
           tr[4*j],ti[4*j], tr[4*j+1],ti[4*j+1], tr[4*j+2],ti[4*j+2], tr[4*j+3],ti[4*j+3]);
  }
#pragma unroll
  for (int j = 0; j < 4; ++j) {
    float ar[4], ai_[4];
#pragma unroll
    for (int k = 0; k < 4; ++k) {
      if (j == 0 || k == 0) { ar[k] = tr[j+4*k]; ai_[k] = ti[j+4*k]; }
      else CMUL(ar[k], ai_[k], tr[j+4*k], ti[j+4*k], W16R[j][k], W16I[j][k]);
    }
    RADIX4(ar[0],ai_[0], ar[1],ai_[1], ar[2],ai_[2], ar[3],ai_[3],
           xr[j],xi[j], xr[j+4],xi[j+4], xr[j+8],xi[j+8], xr[j+12],xi[j+12]);
  }
}

// Wave-level 1024-pt FFT, radices [16,16,4] Stockham. In: xr[k]=x[l+64k] (natural).
// Out: xr[s]=X[l+64s] (natural). Barrier-free (single-wave in-order DS pipe);
// sre/sim are this wave's private 1088-float LDS buffers. All LDS patterns <=2-way.
__device__ __forceinline__ void wave_fft1024(float* xr, float* xi,
                                             float* sre, float* sim,
                                             const float2* __restrict__ twg, int l) {
  dft16(xr, xi);                       // stage 1 (Ns=1): no twiddle
  // store element 16l+k at addr 17l+k
#pragma unroll
  for (int k = 0; k < 16; ++k) { sre[17*l + k] = xr[k]; sim[17*l + k] = xi[k]; }
  __builtin_amdgcn_wave_barrier();
  const int base2 = l + (l >> 4);
#pragma unroll
  for (int k = 0; k < 16; ++k) { xr[k] = sre[base2 + 68*k]; xi[k] = sim[base2 + 68*k]; }
  const int j2 = l & 15;
#pragma unroll
  for (int k = 1; k < 16; ++k) {       // twiddle W256^{j2*k} = twg[4*j2*k]
    float2 w = twg[4 * j2 * k];
    CMUL(xr[k], xi[k], xr[k], xi[k], w.x, w.y);
  }
  dft16(xr, xi);                       // stage 2 (Ns=16)
  const int ob = 272 * (l >> 4) + j2;  // out elem 256(l>>4)+j2+16k at e+(e>>4)
#pragma unroll
  for (int k = 0; k < 16; ++k) { sre[ob + 17*k] = xr[k]; sim[ob + 17*k] = xi[k]; }
  __builtin_amdgcn_wave_barrier();
#pragma unroll
  for (int m = 0; m < 4; ++m) {        // stage 3 (Ns=256, radix-4), j = l+64m
    float ar[4], ai_[4];
#pragma unroll
    for (int k = 0; k < 4; ++k) {
      ar[k] = sre[base2 + 68*m + 272*k];
      ai_[k] = sim[base2 + 68*m + 272*k];
    }
    const int j = l + 64*m;
#pragma unroll
    for (int k = 1; k < 4; ++k) {      // twiddle W1024^{j*k}
      float2 w = twg[j * k];
      CMUL(ar[k], ai_[k], ar[k], ai_[k], w.x, w.y);
    }
    // out bin l+64m+256k -> s = m+4k
    RADIX4(ar[0],ai_[0], ar[1],ai_[1], ar[2],ai_[2], ar[3],ai_[3],
           xr[m],xi[m], xr[m+4],xi[m+4], xr[m+8],xi[m+8], xr[m+12],xi[m+12]);
  }
}

__global__ void k_init(float2* __restrict__ tw, int* __restrict__ mnmx) {
  int g = blockIdx.x * 256 + threadIdx.x;
  if (g < 1024) {
    float ang = -6.283185307179586f * ((float)g / 1024.0f);
    float s, c;
    sincosf(ang, &s, &c);
    tw[g] = make_float2(c, s);
  }
  if (g < BATCH) mnmx[g] = 0x7F800000;       // +inf (min slots)
  else if (g < 2 * BATCH) mnmx[g] = 0;       // 0 (max slots; spec >= 0)
}

// Pass 1: 4 waves/block, 8 consecutive image rows. Per wave: packed row-pair FFT
// (barrier-free), Hermitian unpack (bins 0..512), then block-staged TRANSPOSED
// write -> A^T[v][h] (64B chunks). Kills the standalone transpose kernel.
__global__ __launch_bounds__(256, 4) void k_rowfft(const float* __restrict__ in,
                                                   float2* __restrict__ A,
                                                   const float2* __restrict__ twg) {
  __shared__ float lds[8704];          // 4 waves x 2176; reused as staged[2][8][520]
  const int t  = threadIdx.x;
  const int w  = t >> 6;
  const int l  = t & 63;
  const int bc  = blockIdx.x >> 7;
  const int h0b = (blockIdx.x & 127) << 3;
  const int r0  = h0b + 2 * w;
  float* sre = lds + w * 2176;
  float* sim = sre + 1088;
  const float* row0 = in + ((size_t)bc << 20) + ((size_t)r0 << 10);
  const float* row1 = row0 + N;
  float xr[16], xi[16];
  const float sgn = (l & 1) ? -1.0f : 1.0f;   // (-1)^(h+w), h0 even / h1 odd
#pragma unroll
  for (int k = 0; k < 16; ++k) {
    xr[k] =  sgn * row0[l + 64*k];
    xi[k] = -sgn * row1[l + 64*k];
  }
  wave_fft1024(xr, xi, sre, sim, twg, l);
  // stage Z plain for partner exchange
#pragma unroll
  for (int s = 0; s < 16; ++s) { sre[l + 64*s] = xr[s]; sim[l + 64*s] = xi[s]; }
  __builtin_amdgcn_wave_barrier();
  // Hermitian unpack: A=(P+conj(Q))/2, B=-i(P-conj(Q))/2, Q=Z[(N-i)&1023]
  float arr[9], ari[9], brr[9], bri[9];
#pragma unroll
  for (int s = 0; s < 9; ++s) {
    int i  = l + 64*s;
    int nk = (N - i) & (N - 1);
    float pr = xr[s], pi = xi[s];
    float qr = sre[nk], qi = sim[nk];
    arr[s] = 0.5f * (pr + qr); ari[s] = 0.5f * (pi - qi);
    brr[s] = 0.5f * (pi + qi); bri[s] = 0.5f * (qr - pr);
  }
  __syncthreads();                     // staged region overlays all wave buffers
  float* stre = lds;                   // [8][520]
  float* stim = lds + 4160;
#pragma unroll
  for (int s = 0; s < 9; ++s) {
    int i = l + 64*s;
    if (i <= 512) {
      stre[(2*w)     * 520 + i] = arr[s]; stim[(2*w)     * 520 + i] = ari[s];
      stre[(2*w + 1) * 520 + i] = brr[s]; stim[(2*w + 1) * 520 + i] = bri[s];
    }
  }
  __syncthreads();
  // cooperative transposed write: A^T[v][h0b+r], 8 complex (64B) per chunk
  const int rr = t & 7, v0 = t >> 3;
  float2* Abc = A + ((size_t)bc << 20);
#pragma unroll
  for (int i2 = 0; i2 < 17; ++i2) {
    int v = v0 + 32 * i2;
    if (v <= 512) {
      Abc[(size_t)v * N + h0b + rr] = make_float2(stre[rr*520 + v], stim[rr*520 + v]);
    }
  }
}

// Pass 2: 4 waves/block, 1 column FFT per wave (reads A^T rows coalesced,
// barrier-free FFT), log1p|.| in-register, wave minmax -> atomics, fused
// u-resize for column sx and 2D-Hermitian mirror column N-sx. Writes T1[v][oh].
__global__ __launch_bounds__(256, 4) void k_colfft(const float2* __restrict__ A,
                                                   float* __restrict__ WSf,
                                                   int* __restrict__ mnmx,
                                                   const float2* __restrict__ twg) {
  __shared__ float lds[8704];
  const int t  = threadIdx.x;
  const int w  = t >> 6;
  const int l  = t & 63;
  const int gw = blockIdx.x * 4 + w;   // 0..24623 == BC*513-1 exactly
  const int bc = gw / 513;
  const int sx = gw % 513;
  const int b  = bc / CH;
  float* sre = lds + w * 2176;
  float* sim = sre + 1088;
  const float2* src = A + ((size_t)bc << 20) + ((size_t)sx << 10);
  float xr[16], xi[16];
#pragma unroll
  for (int k = 0; k < 16; ++k) { float2 v = src[l + 64*k]; xr[k] = v.x; xi[k] = v.y; }
  wave_fft1024(xr, xi, sre, sim, twg, l);
  float lmin = 3.4e38f, lmax = 0.0f;
#pragma unroll
  for (int s = 0; s < 16; ++s) {
    float sp = __logf(1.0f + sqrtf(xr[s]*xr[s] + xi[s]*xi[s]));
    sre[l + 64*s] = sp;                // spec plain-indexed in own slice
    lmin = fminf(lmin, sp); lmax = fmaxf(lmax, sp);
  }
#pragma unroll
  for (int off = 32; off; off >>= 1) {
    lmin = fminf(lmin, __shfl_xor(lmin, off));
    lmax = fmaxf(lmax, __shfl_xor(lmax, off));
  }
  if (l == 0) {
    atomicMin(&mnmx[b], __float_as_int(lmin));
    atomicMax(&mnmx[BATCH + b], __float_as_int(lmax));
  }
  __builtin_amdgcn_wave_barrier();
  float* T1 = WSf + ((size_t)bc << 21) + T1OFF;
  const bool mir = (sx != 0) && (sx != 512);
#pragma unroll
  for (int ob = 0; ob < 4; ++ob) {
    int oh = l + 64 * ob;
    if (oh < OUTHW) {
      float x = ((float)oh + 0.5f) * KSCALE - 0.5f;
      int jlo = (int)ceilf(x - KSCALE);  if (jlo < 0) jlo = 0;
      int jhi = (int)floorf(x + KSCALE); if (jhi > N - 1) jhi = N - 1;
      float ssum = 0.0f, acc = 0.0f, accm = 0.0f;
      for (int j = jlo; j <= jhi; ++j) {
        float wgt = 1.0f - fabsf((float)j - x) * SCALE;
        wgt = fmaxf(wgt, 0.0f);
        ssum += wgt;
        acc  += wgt * sre[j];
        accm += wgt * sre[(N - j) & (N - 1)];
      }
      float inv = 1.0f / ssum;
      T1[(size_t)sx * OUTHW + oh] = acc * inv;
      if (mir) T1[(size_t)(N - sx) * OUTHW + oh] = accm * inv;
    }
  }
}

// Pass 3: contract v (T1 rows contiguous per oh-window) + normalization.
__global__ __launch_bounds__(256) void k_resize2(const float2* __restrict__ A,
                                                 const int* __restrict__ mnmx,
                                                 float* __restrict__ out) {
  __shared__ float win[11 * OUTHW];
  const int ow = blockIdx.x % OUTHW;
  const int bc = blockIdx.x / OUTHW;
  const int b  = bc / CH;
  const int t  = threadIdx.x;
  const float* T1 = (const float*)(A + ((size_t)bc << 20)) + T1OFF;
  float x = ((float)ow + 0.5f) * KSCALE - 0.5f;
  int jlo = (int)ceilf(x - KSCALE);  if (jlo < 0) jlo = 0;
  int jhi = (int)floorf(x + KSCALE); if (jhi > N - 1) jhi = N - 1;
  const int nel = (jhi - jlo + 1) * OUTHW;
  const float* src = T1 + (size_t)jlo * OUTHW;
  for (int e = t; e < nel; e += 256) win[e] = src[e];
  __syncthreads();
  const float mn = __int_as_float(mnmx[b]);
  const float mx = __int_as_float(mnmx[BATCH + b]);
  const float inv = 1.0f / (mx - mn + 1e-8f);
  if (t < OUTHW) {
    float ssum = 0.0f, acc = 0.0f;
    for (int j = jlo; j <= jhi; ++j) {
      float wv = 1.0f - fabsf((float)j - x) * SCALE;
      wv = fmaxf(wv, 0.0f);
      ssum += wv;
      acc += wv * win[(j - jlo) * OUTHW + t];
    }
    float v = acc / ssum;
    out[((size_t)bc * OUTHW + t) * OUTHW + ow] = (v - mn) * inv;
  }
}

extern "C" void kernel_launch(void* const* d_in, const int* in_sizes, int n_in,
                              void* d_out, int out_size, void* d_ws, size_t ws_size,
                              hipStream_t stream) {
  const float* in = (const float*)d_in[0];
  float* out = (float*)d_out;
  float2* A = (float2*)d_ws;
  float* WSf = (float*)d_ws;
  int* mnmx = (int*)((char*)d_ws + ABYTES);
  float2* twg = (float2*)((char*)d_ws + ABYTES + 128);

  k_init<<<4, 256, 0, stream>>>(twg, mnmx);
  k_rowfft<<<BC * 128, 256, 0, stream>>>(in, A, twg);
  k_colfft<<<(BC * 513) / 4, 256, 0, stream>>>(A, WSf, mnmx, twg);
  k_resize2<<<BC * OUTHW, 256, 0, stream>>>(A, mnmx, out);
}